// Round 1
// baseline (1038.401 us; speedup 1.0000x reference)
//
#include <hip/hip_runtime.h>

#define N_NODES 50000
#define N_EDGES 1000000
#define EMB     64
#define HID     128
#define NLAYER  3
#define NGRAPH  250
#define XFD     7
#define EFD     5
#define BN_EPS  1e-5f

__device__ __forceinline__ void atomAddF(float* p, float v) {
    // native global_atomic_add_f32, device scope
    __hip_atomic_fetch_add(p, v, __ATOMIC_RELAXED, __HIP_MEMORY_SCOPE_AGENT);
}

// h = x @ xW + xb   (wave-uniform n => x loads broadcast, xW coalesced)
__global__ void k_input(const float* __restrict__ x, const float* __restrict__ xW,
                        const float* __restrict__ xb, float* __restrict__ h) {
    int gid = blockIdx.x * 256 + threadIdx.x;
    if (gid >= N_NODES * EMB) return;
    int n = gid >> 6, f = gid & 63;
    float acc = xb[f];
#pragma unroll
    for (int k = 0; k < XFD; ++k) acc = fmaf(x[n * XFD + k], xW[k * EMB + f], acc);
    h[gid] = acc;
}

// indegree histogram + per-node edge-attr sums (layer-independent!)
__global__ void k_hist(const int* __restrict__ dst, const float* __restrict__ ea,
                       int* __restrict__ deg, float* __restrict__ aggE) {
    int i = blockIdx.x * 256 + threadIdx.x;
    if (i >= N_EDGES) return;
    int d = dst[i];
    atomicAdd(&deg[d], 1);
#pragma unroll
    for (int k = 0; k < EFD; ++k) atomAddF(&aggE[d * EFD + k], ea[i * EFD + k]);
}

// exclusive prefix sum of deg -> rowstart[N+1], cursor[N] (single block, wave scans)
__global__ __launch_bounds__(1024) void k_scan(const int* __restrict__ deg,
                                               int* __restrict__ rowstart,
                                               int* __restrict__ cursor) {
    int tid = threadIdx.x;
    int lane = tid & 63, wid = tid >> 6;
    const int chunk = (N_NODES + 1023) / 1024;  // 49
    int s = tid * chunk;
    int e = min(s + chunk, N_NODES);
    int sum = 0;
    for (int i = s; i < e; ++i) sum += deg[i];
    int x = sum;
#pragma unroll
    for (int off = 1; off < 64; off <<= 1) {
        int y = __shfl_up(x, off);
        if (lane >= off) x += y;
    }
    __shared__ int wsum[16];
    if (lane == 63) wsum[wid] = x;
    __syncthreads();
    int woff = 0;
    for (int w = 0; w < wid; ++w) woff += wsum[w];
    int run = woff + x - sum;  // exclusive prefix for this thread's chunk
    for (int i = s; i < e; ++i) {
        int d = deg[i];
        rowstart[i] = run;
        cursor[i] = run;
        run += d;
    }
    if (tid == 1023) rowstart[N_NODES] = run;
}

// scatter src ids into CSR buckets sorted by dst
__global__ void k_fill(const int* __restrict__ src, const int* __restrict__ dst,
                       int* __restrict__ cursor, int* __restrict__ csr) {
    int i = blockIdx.x * 256 + threadIdx.x;
    if (i >= N_EDGES) return;
    int d = dst[i];
    int p = atomicAdd(&cursor[d], 1);
    csr[p] = src[i];
}

// agg[n] = h[n] + (8*eW[0]+eb) + sum_in h[src] + aggE[n]@eW + indeg*eb
// wave per node; lane = feature; gather loads fully coalesced (256B/edge)
__global__ __launch_bounds__(256) void k_agg(const float* __restrict__ h,
                                             float* __restrict__ agg,
                                             const int* __restrict__ rowstart,
                                             const int* __restrict__ csr,
                                             const float* __restrict__ aggE,
                                             const float* __restrict__ eWl,
                                             const float* __restrict__ ebl) {
    int wid = (blockIdx.x * 256 + threadIdx.x) >> 6;
    int lane = threadIdx.x & 63;
    if (wid >= N_NODES) return;
    int n = wid;
    float ew0 = eWl[0 * 64 + lane], ew1 = eWl[1 * 64 + lane], ew2 = eWl[2 * 64 + lane],
          ew3 = eWl[3 * 64 + lane], ew4 = eWl[4 * 64 + lane];
    float ebf = ebl[lane];
    int j0 = rowstart[n], j1 = rowstart[n + 1];
    float acc = h[n * 64 + lane] + 8.f * ew0 + ebf;  // self-loop: attr [8,0,0,0,0]
    acc += (float)(j1 - j0) * ebf;                   // eb once per real in-edge
    float a0 = aggE[n * 5 + 0], a1 = aggE[n * 5 + 1], a2 = aggE[n * 5 + 2],
          a3 = aggE[n * 5 + 3], a4 = aggE[n * 5 + 4];
    acc = fmaf(a0, ew0, acc);
    acc = fmaf(a1, ew1, acc);
    acc = fmaf(a2, ew2, acc);
    acc = fmaf(a3, ew3, acc);
    acc = fmaf(a4, ew4, acc);
    for (int j = j0; j < j1; ++j) {
        int s = csr[j];
        acc += h[s * 64 + lane];
    }
    agg[n * 64 + lane] = acc;
}

// hidden = relu(agg @ W1 + b1)   tile: 32 nodes x 128 hid, 4x4 per thread
__global__ __launch_bounds__(256) void k_mlp1(const float* __restrict__ agg,
                                              float* __restrict__ hidden,
                                              const float* __restrict__ W1l,
                                              const float* __restrict__ b1l) {
    __shared__ float w1s[64 * 128];  // 32KB, W1[k][j]
    __shared__ float as[32 * 68];    // pad 68: f4-aligned writes, broadcast reads
    __shared__ float b1s[128];
    int tid = threadIdx.x;
    int n0 = blockIdx.x * 32;
    const float4* wg = (const float4*)W1l;
    float4* wsh = (float4*)w1s;
#pragma unroll
    for (int i = 0; i < 8; ++i) wsh[tid + i * 256] = wg[tid + i * 256];
    if (tid < 128) b1s[tid] = b1l[tid];
    const float4* ag4 = (const float4*)agg;
#pragma unroll
    for (int i = 0; i < 2; ++i) {
        int idx = tid + i * 256;  // 512 float4s: m=idx>>4, kq=idx&15
        int m = idx >> 4, kq = idx & 15;
        int nn = n0 + m;
        float4 v = make_float4(0.f, 0.f, 0.f, 0.f);
        if (nn < N_NODES) v = ag4[nn * 16 + kq];
        *(float4*)&as[m * 68 + kq * 4] = v;
    }
    __syncthreads();
    int j0 = (tid & 31) * 4;
    int m0 = (tid >> 5) * 4;
    float acc[4][4] = {};
#pragma unroll 8
    for (int k = 0; k < 64; ++k) {
        float4 w = *(const float4*)&w1s[k * 128 + j0];
        float a0 = as[(m0 + 0) * 68 + k];
        float a1 = as[(m0 + 1) * 68 + k];
        float a2 = as[(m0 + 2) * 68 + k];
        float a3 = as[(m0 + 3) * 68 + k];
        acc[0][0] = fmaf(a0, w.x, acc[0][0]); acc[0][1] = fmaf(a0, w.y, acc[0][1]);
        acc[0][2] = fmaf(a0, w.z, acc[0][2]); acc[0][3] = fmaf(a0, w.w, acc[0][3]);
        acc[1][0] = fmaf(a1, w.x, acc[1][0]); acc[1][1] = fmaf(a1, w.y, acc[1][1]);
        acc[1][2] = fmaf(a1, w.z, acc[1][2]); acc[1][3] = fmaf(a1, w.w, acc[1][3]);
        acc[2][0] = fmaf(a2, w.x, acc[2][0]); acc[2][1] = fmaf(a2, w.y, acc[2][1]);
        acc[2][2] = fmaf(a2, w.z, acc[2][2]); acc[2][3] = fmaf(a2, w.w, acc[2][3]);
        acc[3][0] = fmaf(a3, w.x, acc[3][0]); acc[3][1] = fmaf(a3, w.y, acc[3][1]);
        acc[3][2] = fmaf(a3, w.z, acc[3][2]); acc[3][3] = fmaf(a3, w.w, acc[3][3]);
    }
#pragma unroll
    for (int a = 0; a < 4; ++a) {
        int nn = n0 + m0 + a;
        if (nn < N_NODES) {
            float4 o;
            o.x = fmaxf(acc[a][0] + b1s[j0 + 0], 0.f);
            o.y = fmaxf(acc[a][1] + b1s[j0 + 1], 0.f);
            o.z = fmaxf(acc[a][2] + b1s[j0 + 2], 0.f);
            o.w = fmaxf(acc[a][3] + b1s[j0 + 3], 0.f);
            *(float4*)&hidden[nn * HID + j0] = o;
        }
    }
}

// h2 = hidden @ W2 + b2   tile: 64 nodes x 64 out, 4x4 per thread
__global__ __launch_bounds__(256) void k_mlp2(const float* __restrict__ hidden,
                                              float* __restrict__ h2,
                                              const float* __restrict__ W2l,
                                              const float* __restrict__ b2l) {
    __shared__ float w2s[128 * 64];  // 32KB, W2[k][f]
    __shared__ float hs[64 * 132];   // pad 132
    __shared__ float b2s[64];
    int tid = threadIdx.x;
    int n0 = blockIdx.x * 64;
    const float4* wg = (const float4*)W2l;
    float4* wsh = (float4*)w2s;
#pragma unroll
    for (int i = 0; i < 8; ++i) wsh[tid + i * 256] = wg[tid + i * 256];
    if (tid < 64) b2s[tid] = b2l[tid];
    const float4* hg4 = (const float4*)hidden;
#pragma unroll
    for (int i = 0; i < 8; ++i) {
        int idx = tid + i * 256;  // 2048 float4s: m=idx>>5, kq=idx&31
        int m = idx >> 5, kq = idx & 31;
        int nn = n0 + m;
        float4 v = make_float4(0.f, 0.f, 0.f, 0.f);
        if (nn < N_NODES) v = hg4[nn * 32 + kq];
        *(float4*)&hs[m * 132 + kq * 4] = v;
    }
    __syncthreads();
    int f0 = (tid & 15) * 4;
    int m0 = (tid >> 4) * 4;
    float acc[4][4] = {};
#pragma unroll 8
    for (int k = 0; k < 128; ++k) {
        float4 w = *(const float4*)&w2s[k * 64 + f0];
        float a0 = hs[(m0 + 0) * 132 + k];
        float a1 = hs[(m0 + 1) * 132 + k];
        float a2 = hs[(m0 + 2) * 132 + k];
        float a3 = hs[(m0 + 3) * 132 + k];
        acc[0][0] = fmaf(a0, w.x, acc[0][0]); acc[0][1] = fmaf(a0, w.y, acc[0][1]);
        acc[0][2] = fmaf(a0, w.z, acc[0][2]); acc[0][3] = fmaf(a0, w.w, acc[0][3]);
        acc[1][0] = fmaf(a1, w.x, acc[1][0]); acc[1][1] = fmaf(a1, w.y, acc[1][1]);
        acc[1][2] = fmaf(a1, w.z, acc[1][2]); acc[1][3] = fmaf(a1, w.w, acc[1][3]);
        acc[2][0] = fmaf(a2, w.x, acc[2][0]); acc[2][1] = fmaf(a2, w.y, acc[2][1]);
        acc[2][2] = fmaf(a2, w.z, acc[2][2]); acc[2][3] = fmaf(a2, w.w, acc[2][3]);
        acc[3][0] = fmaf(a3, w.x, acc[3][0]); acc[3][1] = fmaf(a3, w.y, acc[3][1]);
        acc[3][2] = fmaf(a3, w.z, acc[3][2]); acc[3][3] = fmaf(a3, w.w, acc[3][3]);
    }
#pragma unroll
    for (int a = 0; a < 4; ++a) {
        int nn = n0 + m0 + a;
        if (nn < N_NODES) {
            float4 o;
            o.x = acc[a][0] + b2s[f0 + 0];
            o.y = acc[a][1] + b2s[f0 + 1];
            o.z = acc[a][2] + b2s[f0 + 2];
            o.w = acc[a][3] + b2s[f0 + 3];
            *(float4*)&h2[nn * EMB + f0] = o;
        }
    }
}

// per-feature sum & sumsq for batchnorm (stats[0..63]=sum, [64..127]=sumsq)
__global__ __launch_bounds__(256) void k_stats(const float* __restrict__ h2,
                                               float* __restrict__ stats) {
    int f = threadIdx.x & 63, rg = threadIdx.x >> 6;
    float s = 0.f, q = 0.f;
    for (int n = blockIdx.x * 4 + rg; n < N_NODES; n += gridDim.x * 4) {
        float v = h2[n * 64 + f];
        s += v;
        q = fmaf(v, v, q);
    }
    __shared__ float ls[4][64], lq[4][64];
    ls[rg][f] = s;
    lq[rg][f] = q;
    __syncthreads();
    if (rg == 0) {
        s = ls[0][f] + ls[1][f] + ls[2][f] + ls[3][f];
        q = lq[0][f] + lq[1][f] + lq[2][f] + lq[3][f];
        atomAddF(&stats[f], s);
        atomAddF(&stats[64 + f], q);
    }
}

// BN apply (+ ELU except last layer)
__global__ void k_bn(const float* __restrict__ h2, float* __restrict__ h,
                     const float* __restrict__ stats, const float* __restrict__ gam,
                     const float* __restrict__ bet, int apply_elu) {
    int gid = blockIdx.x * 256 + threadIdx.x;
    if (gid >= N_NODES * EMB) return;
    int f = gid & 63;
    const float invN = 1.f / (float)N_NODES;
    float mean = stats[f] * invN;
    float var = stats[64 + f] * invN - mean * mean;
    float inv = rsqrtf(var + BN_EPS);
    float v = (h2[gid] - mean) * inv * gam[f] + bet[f];
    if (apply_elu) v = v > 0.f ? v : expm1f(v);
    h[gid] = v;
}

__global__ void k_out(const float* __restrict__ h, const int* __restrict__ last,
                      float* __restrict__ out) {
    int gid = blockIdx.x * 256 + threadIdx.x;
    if (gid >= NGRAPH * EMB) return;
    int b = gid >> 6, f = gid & 63;
    out[gid] = h[last[b] * EMB + f];
}

extern "C" void kernel_launch(void* const* d_in, const int* in_sizes, int n_in,
                              void* d_out, int out_size, void* d_ws, size_t ws_size,
                              hipStream_t stream) {
    const float* x   = (const float*)d_in[0];
    const float* ea  = (const float*)d_in[1];
    const int*   eidx= (const int*)d_in[2];
    const int*   last= (const int*)d_in[3];
    const float* xW  = (const float*)d_in[4];
    const float* xb  = (const float*)d_in[5];
    const float* eW  = (const float*)d_in[6];
    const float* eb  = (const float*)d_in[7];
    const float* W1  = (const float*)d_in[8];
    const float* b1  = (const float*)d_in[9];
    const float* W2  = (const float*)d_in[10];
    const float* b2  = (const float*)d_in[11];
    const float* gam = (const float*)d_in[12];
    const float* bet = (const float*)d_in[13];
    float* out = (float*)d_out;

    const int* srcI = eidx;            // edge_index[0]
    const int* dstI = eidx + N_EDGES;  // edge_index[1]

    // workspace carve-up (~57 MB)
    float* h      = (float*)d_ws;              // N*64
    float* agg    = h + N_NODES * EMB;         // N*64 (reused as h2)
    float* hidden = agg + N_NODES * EMB;       // N*128
    float* aggE   = hidden + N_NODES * HID;    // N*5
    float* stats  = aggE + N_NODES * EFD;      // L*128
    int* deg      = (int*)(stats + NLAYER * 2 * EMB);  // N
    int* rowstart = deg + N_NODES;             // N+1
    int* cursor   = rowstart + N_NODES + 1;    // N
    int* csr      = cursor + N_NODES;          // E

    hipMemsetAsync(deg, 0, N_NODES * sizeof(int), stream);
    hipMemsetAsync(aggE, 0, N_NODES * EFD * sizeof(float), stream);
    hipMemsetAsync(stats, 0, NLAYER * 2 * EMB * sizeof(float), stream);

    k_input<<<(N_NODES * EMB + 255) / 256, 256, 0, stream>>>(x, xW, xb, h);
    k_hist<<<(N_EDGES + 255) / 256, 256, 0, stream>>>(dstI, ea, deg, aggE);
    k_scan<<<1, 1024, 0, stream>>>(deg, rowstart, cursor);
    k_fill<<<(N_EDGES + 255) / 256, 256, 0, stream>>>(srcI, dstI, cursor, csr);

    for (int l = 0; l < NLAYER; ++l) {
        k_agg<<<(N_NODES * 64 + 255) / 256, 256, 0, stream>>>(
            h, agg, rowstart, csr, aggE, eW + l * EFD * EMB, eb + l * EMB);
        k_mlp1<<<(N_NODES + 31) / 32, 256, 0, stream>>>(agg, hidden, W1 + l * EMB * HID,
                                                        b1 + l * HID);
        k_mlp2<<<(N_NODES + 63) / 64, 256, 0, stream>>>(hidden, agg, W2 + l * HID * EMB,
                                                        b2 + l * EMB);
        k_stats<<<512, 256, 0, stream>>>(agg, stats + l * 2 * EMB);
        k_bn<<<(N_NODES * EMB + 255) / 256, 256, 0, stream>>>(
            agg, h, stats + l * 2 * EMB, gam + l * EMB, bet + l * EMB,
            (l < NLAYER - 1) ? 1 : 0);
    }
    k_out<<<(NGRAPH * EMB + 255) / 256, 256, 0, stream>>>(h, last, out);
}

// Round 2
// 635.055 us; speedup vs baseline: 1.6351x; 1.6351x over previous
//
#include <hip/hip_runtime.h>

#define N_NODES 50000
#define N_EDGES 1000000
#define EMB     64
#define HID     128
#define NLAYER  3
#define NGRAPH  250
#define XFD     7
#define EFD     5
#define BN_EPS  1e-5f

__device__ __forceinline__ void atomAddF(float* p, float v) {
    __hip_atomic_fetch_add(p, v, __ATOMIC_RELAXED, __HIP_MEMORY_SCOPE_AGENT);
}

// h = x @ xW + xb
__global__ void k_input(const float* __restrict__ x, const float* __restrict__ xW,
                        const float* __restrict__ xb, float* __restrict__ h) {
    int gid = blockIdx.x * 256 + threadIdx.x;
    if (gid >= N_NODES * EMB) return;
    int n = gid >> 6, f = gid & 63;
    float acc = xb[f];
#pragma unroll
    for (int k = 0; k < XFD; ++k) acc = fmaf(x[n * XFD + k], xW[k * EMB + f], acc);
    h[gid] = acc;
}

// indegree histogram only (int atomics; float scatter removed — R1: 187MB atomic
// writethrough traffic made this 290us)
__global__ void k_hist(const int* __restrict__ dst, int* __restrict__ deg) {
    int i = blockIdx.x * 256 + threadIdx.x;
    if (i >= N_EDGES) return;
    atomicAdd(&deg[dst[i]], 1);
}

// exclusive prefix sum of deg -> rowstart[N+1], cursor[N] (single block)
__global__ __launch_bounds__(1024) void k_scan(const int* __restrict__ deg,
                                               int* __restrict__ rowstart,
                                               int* __restrict__ cursor) {
    int tid = threadIdx.x;
    int lane = tid & 63, wid = tid >> 6;
    const int chunk = (N_NODES + 1023) / 1024;  // 49
    int s = tid * chunk;
    int e = min(s + chunk, N_NODES);
    int sum = 0;
    for (int i = s; i < e; ++i) sum += deg[i];
    int x = sum;
#pragma unroll
    for (int off = 1; off < 64; off <<= 1) {
        int y = __shfl_up(x, off);
        if (lane >= off) x += y;
    }
    __shared__ int wsum[16];
    if (lane == 63) wsum[wid] = x;
    __syncthreads();
    int woff = 0;
    for (int w = 0; w < wid; ++w) woff += wsum[w];
    int run = woff + x - sum;
    for (int i = s; i < e; ++i) {
        int d = deg[i];
        rowstart[i] = run;
        cursor[i] = run;
        run += d;
    }
    if (tid == 1023) rowstart[N_NODES] = run;
}

// scatter src ids AND edge ids into CSR buckets sorted by dst
__global__ void k_fill(const int* __restrict__ src, const int* __restrict__ dst,
                       int* __restrict__ cursor, int* __restrict__ csr,
                       int* __restrict__ csrE) {
    int i = blockIdx.x * 256 + threadIdx.x;
    if (i >= N_EDGES) return;
    int d = dst[i];
    int p = atomicAdd(&cursor[d], 1);
    csr[p] = src[i];
    csrE[p] = i;
}

// aggE[n] = sum over in-edges of ea[eid]  (deterministic gather, no atomics)
// wave per node: lanes parallel over edges, shuffle-reduce 5 feature sums
__global__ __launch_bounds__(256) void k_aggE(const int* __restrict__ rowstart,
                                              const int* __restrict__ csrE,
                                              const float* __restrict__ ea,
                                              float* __restrict__ aggE) {
    int wid = (blockIdx.x * 256 + threadIdx.x) >> 6;
    int lane = threadIdx.x & 63;
    if (wid >= N_NODES) return;
    int j0 = rowstart[wid], j1 = rowstart[wid + 1];
    float s0 = 0.f, s1 = 0.f, s2 = 0.f, s3 = 0.f, s4 = 0.f;
    for (int j = j0 + lane; j < j1; j += 64) {
        int e = csrE[j];
        const float* p = ea + e * EFD;
        s0 += p[0]; s1 += p[1]; s2 += p[2]; s3 += p[3]; s4 += p[4];
    }
#pragma unroll
    for (int off = 32; off; off >>= 1) {
        s0 += __shfl_down(s0, off);
        s1 += __shfl_down(s1, off);
        s2 += __shfl_down(s2, off);
        s3 += __shfl_down(s3, off);
        s4 += __shfl_down(s4, off);
    }
    if (lane == 0) {
        float* o = aggE + wid * EFD;
        o[0] = s0; o[1] = s1; o[2] = s2; o[3] = s3; o[4] = s4;
    }
}

// agg[n] = h[n] + (8*eW[0]+eb) + sum_in h[src] + aggE[n]@eW + indeg*eb
// wave per node; lane = feature. csr entries loaded coalesced by lanes then
// shfl-broadcast: removes the serial csr->h dependent-load latency chain.
__global__ __launch_bounds__(256) void k_agg(const float* __restrict__ h,
                                             float* __restrict__ agg,
                                             const int* __restrict__ rowstart,
                                             const int* __restrict__ csr,
                                             const float* __restrict__ aggE,
                                             const float* __restrict__ eWl,
                                             const float* __restrict__ ebl) {
    int wid = (blockIdx.x * 256 + threadIdx.x) >> 6;
    int lane = threadIdx.x & 63;
    if (wid >= N_NODES) return;
    int n = wid;
    float ew0 = eWl[0 * 64 + lane], ew1 = eWl[1 * 64 + lane], ew2 = eWl[2 * 64 + lane],
          ew3 = eWl[3 * 64 + lane], ew4 = eWl[4 * 64 + lane];
    float ebf = ebl[lane];
    int j0 = rowstart[n], j1 = rowstart[n + 1];
    float acc = h[n * 64 + lane] + 8.f * ew0 + ebf;  // self-loop attr [8,0,0,0,0]
    acc += (float)(j1 - j0) * ebf;
    float a0 = aggE[n * 5 + 0], a1 = aggE[n * 5 + 1], a2 = aggE[n * 5 + 2],
          a3 = aggE[n * 5 + 3], a4 = aggE[n * 5 + 4];
    acc = fmaf(a0, ew0, acc);
    acc = fmaf(a1, ew1, acc);
    acc = fmaf(a2, ew2, acc);
    acc = fmaf(a3, ew3, acc);
    acc = fmaf(a4, ew4, acc);
    while (j0 < j1) {
        int take = j1 - j0;
        if (take > 64) take = 64;
        int myid = (lane < take) ? csr[j0 + lane] : 0;
        int k = 0;
        for (; k + 4 <= take; k += 4) {
            int s0 = __shfl(myid, k + 0), s1 = __shfl(myid, k + 1),
                s2 = __shfl(myid, k + 2), s3 = __shfl(myid, k + 3);
            float v0 = h[s0 * 64 + lane];
            float v1 = h[s1 * 64 + lane];
            float v2 = h[s2 * 64 + lane];
            float v3 = h[s3 * 64 + lane];
            acc += ((v0 + v1) + (v2 + v3));
        }
        for (; k < take; ++k) {
            int s = __shfl(myid, k);
            acc += h[s * 64 + lane];
        }
        j0 += take;
    }
    agg[n * 64 + lane] = acc;
}

// hidden = relu(agg @ W1 + b1)   tile: 32 nodes x 128 hid, 4x4 per thread
__global__ __launch_bounds__(256) void k_mlp1(const float* __restrict__ agg,
                                              float* __restrict__ hidden,
                                              const float* __restrict__ W1l,
                                              const float* __restrict__ b1l) {
    __shared__ float w1s[64 * 128];
    __shared__ float as[32 * 68];
    __shared__ float b1s[128];
    int tid = threadIdx.x;
    int n0 = blockIdx.x * 32;
    const float4* wg = (const float4*)W1l;
    float4* wsh = (float4*)w1s;
#pragma unroll
    for (int i = 0; i < 8; ++i) wsh[tid + i * 256] = wg[tid + i * 256];
    if (tid < 128) b1s[tid] = b1l[tid];
    const float4* ag4 = (const float4*)agg;
#pragma unroll
    for (int i = 0; i < 2; ++i) {
        int idx = tid + i * 256;
        int m = idx >> 4, kq = idx & 15;
        int nn = n0 + m;
        float4 v = make_float4(0.f, 0.f, 0.f, 0.f);
        if (nn < N_NODES) v = ag4[nn * 16 + kq];
        *(float4*)&as[m * 68 + kq * 4] = v;
    }
    __syncthreads();
    int j0 = (tid & 31) * 4;
    int m0 = (tid >> 5) * 4;
    float acc[4][4] = {};
#pragma unroll 8
    for (int k = 0; k < 64; ++k) {
        float4 w = *(const float4*)&w1s[k * 128 + j0];
        float a0 = as[(m0 + 0) * 68 + k];
        float a1 = as[(m0 + 1) * 68 + k];
        float a2 = as[(m0 + 2) * 68 + k];
        float a3 = as[(m0 + 3) * 68 + k];
        acc[0][0] = fmaf(a0, w.x, acc[0][0]); acc[0][1] = fmaf(a0, w.y, acc[0][1]);
        acc[0][2] = fmaf(a0, w.z, acc[0][2]); acc[0][3] = fmaf(a0, w.w, acc[0][3]);
        acc[1][0] = fmaf(a1, w.x, acc[1][0]); acc[1][1] = fmaf(a1, w.y, acc[1][1]);
        acc[1][2] = fmaf(a1, w.z, acc[1][2]); acc[1][3] = fmaf(a1, w.w, acc[1][3]);
        acc[2][0] = fmaf(a2, w.x, acc[2][0]); acc[2][1] = fmaf(a2, w.y, acc[2][1]);
        acc[2][2] = fmaf(a2, w.z, acc[2][2]); acc[2][3] = fmaf(a2, w.w, acc[2][3]);
        acc[3][0] = fmaf(a3, w.x, acc[3][0]); acc[3][1] = fmaf(a3, w.y, acc[3][1]);
        acc[3][2] = fmaf(a3, w.z, acc[3][2]); acc[3][3] = fmaf(a3, w.w, acc[3][3]);
    }
#pragma unroll
    for (int a = 0; a < 4; ++a) {
        int nn = n0 + m0 + a;
        if (nn < N_NODES) {
            float4 o;
            o.x = fmaxf(acc[a][0] + b1s[j0 + 0], 0.f);
            o.y = fmaxf(acc[a][1] + b1s[j0 + 1], 0.f);
            o.z = fmaxf(acc[a][2] + b1s[j0 + 2], 0.f);
            o.w = fmaxf(acc[a][3] + b1s[j0 + 3], 0.f);
            *(float4*)&hidden[nn * HID + j0] = o;
        }
    }
}

// h2 = hidden @ W2 + b2   tile: 64 nodes x 64 out, 4x4 per thread
__global__ __launch_bounds__(256) void k_mlp2(const float* __restrict__ hidden,
                                              float* __restrict__ h2,
                                              const float* __restrict__ W2l,
                                              const float* __restrict__ b2l) {
    __shared__ float w2s[128 * 64];
    __shared__ float hs[64 * 132];
    __shared__ float b2s[64];
    int tid = threadIdx.x;
    int n0 = blockIdx.x * 64;
    const float4* wg = (const float4*)W2l;
    float4* wsh = (float4*)w2s;
#pragma unroll
    for (int i = 0; i < 8; ++i) wsh[tid + i * 256] = wg[tid + i * 256];
    if (tid < 64) b2s[tid] = b2l[tid];
    const float4* hg4 = (const float4*)hidden;
#pragma unroll
    for (int i = 0; i < 8; ++i) {
        int idx = tid + i * 256;
        int m = idx >> 5, kq = idx & 31;
        int nn = n0 + m;
        float4 v = make_float4(0.f, 0.f, 0.f, 0.f);
        if (nn < N_NODES) v = hg4[nn * 32 + kq];
        *(float4*)&hs[m * 132 + kq * 4] = v;
    }
    __syncthreads();
    int f0 = (tid & 15) * 4;
    int m0 = (tid >> 4) * 4;
    float acc[4][4] = {};
#pragma unroll 8
    for (int k = 0; k < 128; ++k) {
        float4 w = *(const float4*)&w2s[k * 64 + f0];
        float a0 = hs[(m0 + 0) * 132 + k];
        float a1 = hs[(m0 + 1) * 132 + k];
        float a2 = hs[(m0 + 2) * 132 + k];
        float a3 = hs[(m0 + 3) * 132 + k];
        acc[0][0] = fmaf(a0, w.x, acc[0][0]); acc[0][1] = fmaf(a0, w.y, acc[0][1]);
        acc[0][2] = fmaf(a0, w.z, acc[0][2]); acc[0][3] = fmaf(a0, w.w, acc[0][3]);
        acc[1][0] = fmaf(a1, w.x, acc[1][0]); acc[1][1] = fmaf(a1, w.y, acc[1][1]);
        acc[1][2] = fmaf(a1, w.z, acc[1][2]); acc[1][3] = fmaf(a1, w.w, acc[1][3]);
        acc[2][0] = fmaf(a2, w.x, acc[2][0]); acc[2][1] = fmaf(a2, w.y, acc[2][1]);
        acc[2][2] = fmaf(a2, w.z, acc[2][2]); acc[2][3] = fmaf(a2, w.w, acc[2][3]);
        acc[3][0] = fmaf(a3, w.x, acc[3][0]); acc[3][1] = fmaf(a3, w.y, acc[3][1]);
        acc[3][2] = fmaf(a3, w.z, acc[3][2]); acc[3][3] = fmaf(a3, w.w, acc[3][3]);
    }
#pragma unroll
    for (int a = 0; a < 4; ++a) {
        int nn = n0 + m0 + a;
        if (nn < N_NODES) {
            float4 o;
            o.x = acc[a][0] + b2s[f0 + 0];
            o.y = acc[a][1] + b2s[f0 + 1];
            o.z = acc[a][2] + b2s[f0 + 2];
            o.w = acc[a][3] + b2s[f0 + 3];
            *(float4*)&h2[nn * EMB + f0] = o;
        }
    }
}

// per-feature sum & sumsq for batchnorm
__global__ __launch_bounds__(256) void k_stats(const float* __restrict__ h2,
                                               float* __restrict__ stats) {
    int f = threadIdx.x & 63, rg = threadIdx.x >> 6;
    float s = 0.f, q = 0.f;
    for (int n = blockIdx.x * 4 + rg; n < N_NODES; n += gridDim.x * 4) {
        float v = h2[n * 64 + f];
        s += v;
        q = fmaf(v, v, q);
    }
    __shared__ float ls[4][64], lq[4][64];
    ls[rg][f] = s;
    lq[rg][f] = q;
    __syncthreads();
    if (rg == 0) {
        s = ls[0][f] + ls[1][f] + ls[2][f] + ls[3][f];
        q = lq[0][f] + lq[1][f] + lq[2][f] + lq[3][f];
        atomAddF(&stats[f], s);
        atomAddF(&stats[64 + f], q);
    }
}

// BN apply (+ ELU except last layer)
__global__ void k_bn(const float* __restrict__ h2, float* __restrict__ h,
                     const float* __restrict__ stats, const float* __restrict__ gam,
                     const float* __restrict__ bet, int apply_elu) {
    int gid = blockIdx.x * 256 + threadIdx.x;
    if (gid >= N_NODES * EMB) return;
    int f = gid & 63;
    const float invN = 1.f / (float)N_NODES;
    float mean = stats[f] * invN;
    float var = stats[64 + f] * invN - mean * mean;
    float inv = rsqrtf(var + BN_EPS);
    float v = (h2[gid] - mean) * inv * gam[f] + bet[f];
    if (apply_elu) v = v > 0.f ? v : expm1f(v);
    h[gid] = v;
}

__global__ void k_out(const float* __restrict__ h, const int* __restrict__ last,
                      float* __restrict__ out) {
    int gid = blockIdx.x * 256 + threadIdx.x;
    if (gid >= NGRAPH * EMB) return;
    int b = gid >> 6, f = gid & 63;
    out[gid] = h[last[b] * EMB + f];
}

extern "C" void kernel_launch(void* const* d_in, const int* in_sizes, int n_in,
                              void* d_out, int out_size, void* d_ws, size_t ws_size,
                              hipStream_t stream) {
    const float* x   = (const float*)d_in[0];
    const float* ea  = (const float*)d_in[1];
    const int*   eidx= (const int*)d_in[2];
    const int*   last= (const int*)d_in[3];
    const float* xW  = (const float*)d_in[4];
    const float* xb  = (const float*)d_in[5];
    const float* eW  = (const float*)d_in[6];
    const float* eb  = (const float*)d_in[7];
    const float* W1  = (const float*)d_in[8];
    const float* b1  = (const float*)d_in[9];
    const float* W2  = (const float*)d_in[10];
    const float* b2  = (const float*)d_in[11];
    const float* gam = (const float*)d_in[12];
    const float* bet = (const float*)d_in[13];
    float* out = (float*)d_out;

    const int* srcI = eidx;
    const int* dstI = eidx + N_EDGES;

    // workspace carve-up (same footprint as R1; csrE aliases `hidden`, which
    // is first written by k_mlp1 — strictly after k_aggE completes)
    float* h      = (float*)d_ws;              // N*64
    float* agg    = h + N_NODES * EMB;         // N*64 (reused as h2)
    float* hidden = agg + N_NODES * EMB;       // N*128
    float* aggE   = hidden + N_NODES * HID;    // N*5
    float* stats  = aggE + N_NODES * EFD;      // L*128
    int* deg      = (int*)(stats + NLAYER * 2 * EMB);  // N
    int* rowstart = deg + N_NODES;             // N+1
    int* cursor   = rowstart + N_NODES + 1;    // N
    int* csr      = cursor + N_NODES;          // E
    int* csrE     = (int*)hidden;              // E (alias, pre-layer-loop only)

    hipMemsetAsync(deg, 0, N_NODES * sizeof(int), stream);
    hipMemsetAsync(stats, 0, NLAYER * 2 * EMB * sizeof(float), stream);

    k_input<<<(N_NODES * EMB + 255) / 256, 256, 0, stream>>>(x, xW, xb, h);
    k_hist<<<(N_EDGES + 255) / 256, 256, 0, stream>>>(dstI, deg);
    k_scan<<<1, 1024, 0, stream>>>(deg, rowstart, cursor);
    k_fill<<<(N_EDGES + 255) / 256, 256, 0, stream>>>(srcI, dstI, cursor, csr, csrE);
    k_aggE<<<(N_NODES * 64 + 255) / 256, 256, 0, stream>>>(rowstart, csrE, ea, aggE);

    for (int l = 0; l < NLAYER; ++l) {
        k_agg<<<(N_NODES * 64 + 255) / 256, 256, 0, stream>>>(
            h, agg, rowstart, csr, aggE, eW + l * EFD * EMB, eb + l * EMB);
        k_mlp1<<<(N_NODES + 31) / 32, 256, 0, stream>>>(agg, hidden, W1 + l * EMB * HID,
                                                        b1 + l * HID);
        k_mlp2<<<(N_NODES + 63) / 64, 256, 0, stream>>>(hidden, agg, W2 + l * HID * EMB,
                                                        b2 + l * EMB);
        k_stats<<<512, 256, 0, stream>>>(agg, stats + l * 2 * EMB);
        k_bn<<<(N_NODES * EMB + 255) / 256, 256, 0, stream>>>(
            agg, h, stats + l * 2 * EMB, gam + l * EMB, bet + l * EMB,
            (l < NLAYER - 1) ? 1 : 0);
    }
    k_out<<<(NGRAPH * EMB + 255) / 256, 256, 0, stream>>>(h, last, out);
}

// Round 3
// 509.824 us; speedup vs baseline: 2.0368x; 1.2456x over previous
//
#include <hip/hip_runtime.h>

#define N_NODES 50000
#define N_EDGES 1000000
#define EMB     64
#define HID     128
#define NLAYER  3
#define NGRAPH  250
#define XFD     7
#define EFD     5
#define BN_EPS  1e-5f
#define NB_SCAN 196  // ceil(50000/256)

__device__ __forceinline__ void atomAddF(float* p, float v) {
    __hip_atomic_fetch_add(p, v, __ATOMIC_RELAXED, __HIP_MEMORY_SCOPE_AGENT);
}

// h = x @ xW + xb
__global__ void k_input(const float* __restrict__ x, const float* __restrict__ xW,
                        const float* __restrict__ xb, float* __restrict__ h) {
    int gid = blockIdx.x * 256 + threadIdx.x;
    if (gid >= N_NODES * EMB) return;
    int n = gid >> 6, f = gid & 63;
    float acc = xb[f];
#pragma unroll
    for (int k = 0; k < XFD; ++k) acc = fmaf(x[n * XFD + k], xW[k * EMB + f], acc);
    h[gid] = acc;
}

// indegree histogram (int atomics only)
__global__ void k_hist(const int* __restrict__ dst, int* __restrict__ deg) {
    int i = blockIdx.x * 256 + threadIdx.x;
    if (i >= N_EDGES) return;
    atomicAdd(&deg[dst[i]], 1);
}

// ---- 3-phase multi-block exclusive scan (R2: single-block scan was 108us,
// occupancy 0.14% — one CU. Split across 196 blocks.) ----
__global__ __launch_bounds__(256) void k_scanA(const int* __restrict__ deg,
                                               int* __restrict__ bsum) {
    int tid = threadIdx.x, lane = tid & 63, wid = tid >> 6;
    int i = blockIdx.x * 256 + tid;
    int v = (i < N_NODES) ? deg[i] : 0;
#pragma unroll
    for (int off = 32; off; off >>= 1) v += __shfl_down(v, off);
    __shared__ int ws[4];
    if (lane == 0) ws[wid] = v;
    __syncthreads();
    if (tid == 0) bsum[blockIdx.x] = ws[0] + ws[1] + ws[2] + ws[3];
}

__global__ __launch_bounds__(256) void k_scanB(const int* __restrict__ bsum,
                                               int* __restrict__ boff) {
    int tid = threadIdx.x, lane = tid & 63, wid = tid >> 6;
    int v = (tid < NB_SCAN) ? bsum[tid] : 0;
    int x = v;
#pragma unroll
    for (int off = 1; off < 64; off <<= 1) {
        int y = __shfl_up(x, off);
        if (lane >= off) x += y;
    }
    __shared__ int wtot[4];
    if (lane == 63) wtot[wid] = x;
    __syncthreads();
    int woff = 0;
    for (int w = 0; w < wid; ++w) woff += wtot[w];
    if (tid < NB_SCAN) boff[tid] = woff + x - v;  // exclusive
}

__global__ __launch_bounds__(256) void k_scanC(const int* __restrict__ deg,
                                               const int* __restrict__ boff,
                                               int* __restrict__ rowstart,
                                               int* __restrict__ cursor) {
    int tid = threadIdx.x, lane = tid & 63, wid = tid >> 6;
    int i = blockIdx.x * 256 + tid;
    int v = (i < N_NODES) ? deg[i] : 0;
    int x = v;
#pragma unroll
    for (int off = 1; off < 64; off <<= 1) {
        int y = __shfl_up(x, off);
        if (lane >= off) x += y;
    }
    __shared__ int wtot[4];
    if (lane == 63) wtot[wid] = x;
    __syncthreads();
    int woff = boff[blockIdx.x];
    for (int w = 0; w < wid; ++w) woff += wtot[w];
    int excl = woff + x - v;
    if (i < N_NODES) {
        rowstart[i] = excl;
        cursor[i] = excl;
        if (i == N_NODES - 1) rowstart[N_NODES] = excl + v;
    }
}

// scatter src ids AND edge ids into CSR buckets sorted by dst
__global__ void k_fill(const int* __restrict__ src, const int* __restrict__ dst,
                       int* __restrict__ cursor, int* __restrict__ csr,
                       int* __restrict__ csrE) {
    int i = blockIdx.x * 256 + threadIdx.x;
    if (i >= N_EDGES) return;
    int d = dst[i];
    int p = atomicAdd(&cursor[d], 1);
    csr[p] = src[i];
    csrE[p] = i;
}

// aggE[n] = sum over in-edges of ea[eid]  (deterministic gather, no atomics)
__global__ __launch_bounds__(256) void k_aggE(const int* __restrict__ rowstart,
                                              const int* __restrict__ csrE,
                                              const float* __restrict__ ea,
                                              float* __restrict__ aggE) {
    int wid = (blockIdx.x * 256 + threadIdx.x) >> 6;
    int lane = threadIdx.x & 63;
    if (wid >= N_NODES) return;
    int j0 = rowstart[wid], j1 = rowstart[wid + 1];
    float s0 = 0.f, s1 = 0.f, s2 = 0.f, s3 = 0.f, s4 = 0.f;
    for (int j = j0 + lane; j < j1; j += 64) {
        int e = csrE[j];
        const float* p = ea + e * EFD;
        s0 += p[0]; s1 += p[1]; s2 += p[2]; s3 += p[3]; s4 += p[4];
    }
#pragma unroll
    for (int off = 32; off; off >>= 1) {
        s0 += __shfl_down(s0, off);
        s1 += __shfl_down(s1, off);
        s2 += __shfl_down(s2, off);
        s3 += __shfl_down(s3, off);
        s4 += __shfl_down(s4, off);
    }
    if (lane == 0) {
        float* o = aggE + wid * EFD;
        o[0] = s0; o[1] = s1; o[2] = s2; o[3] = s3; o[4] = s4;
    }
}

// agg[n] = h[n] + (8*eW[0]+eb) + sum_in h[src] + aggE[n]@eW + indeg*eb
__global__ __launch_bounds__(256) void k_agg(const float* __restrict__ h,
                                             float* __restrict__ agg,
                                             const int* __restrict__ rowstart,
                                             const int* __restrict__ csr,
                                             const float* __restrict__ aggE,
                                             const float* __restrict__ eWl,
                                             const float* __restrict__ ebl) {
    int wid = (blockIdx.x * 256 + threadIdx.x) >> 6;
    int lane = threadIdx.x & 63;
    if (wid >= N_NODES) return;
    int n = wid;
    float ew0 = eWl[0 * 64 + lane], ew1 = eWl[1 * 64 + lane], ew2 = eWl[2 * 64 + lane],
          ew3 = eWl[3 * 64 + lane], ew4 = eWl[4 * 64 + lane];
    float ebf = ebl[lane];
    int j0 = rowstart[n], j1 = rowstart[n + 1];
    float acc = h[n * 64 + lane] + 8.f * ew0 + ebf;  // self-loop attr [8,0,0,0,0]
    acc += (float)(j1 - j0) * ebf;
    float a0 = aggE[n * 5 + 0], a1 = aggE[n * 5 + 1], a2 = aggE[n * 5 + 2],
          a3 = aggE[n * 5 + 3], a4 = aggE[n * 5 + 4];
    acc = fmaf(a0, ew0, acc);
    acc = fmaf(a1, ew1, acc);
    acc = fmaf(a2, ew2, acc);
    acc = fmaf(a3, ew3, acc);
    acc = fmaf(a4, ew4, acc);
    while (j0 < j1) {
        int take = j1 - j0;
        if (take > 64) take = 64;
        int myid = (lane < take) ? csr[j0 + lane] : 0;
        int k = 0;
        for (; k + 4 <= take; k += 4) {
            int s0 = __shfl(myid, k + 0), s1 = __shfl(myid, k + 1),
                s2 = __shfl(myid, k + 2), s3 = __shfl(myid, k + 3);
            float v0 = h[s0 * 64 + lane];
            float v1 = h[s1 * 64 + lane];
            float v2 = h[s2 * 64 + lane];
            float v3 = h[s3 * 64 + lane];
            acc += ((v0 + v1) + (v2 + v3));
        }
        for (; k < take; ++k) {
            int s = __shfl(myid, k);
            acc += h[s * 64 + lane];
        }
        j0 += take;
    }
    agg[n * 64 + lane] = acc;
}

// hidden = relu(agg @ W1 + b1)   tile: 32 nodes x 128 hid, 4x4 per thread
__global__ __launch_bounds__(256) void k_mlp1(const float* __restrict__ agg,
                                              float* __restrict__ hidden,
                                              const float* __restrict__ W1l,
                                              const float* __restrict__ b1l) {
    __shared__ float w1s[64 * 128];
    __shared__ float as[32 * 68];
    __shared__ float b1s[128];
    int tid = threadIdx.x;
    int n0 = blockIdx.x * 32;
    const float4* wg = (const float4*)W1l;
    float4* wsh = (float4*)w1s;
#pragma unroll
    for (int i = 0; i < 8; ++i) wsh[tid + i * 256] = wg[tid + i * 256];
    if (tid < 128) b1s[tid] = b1l[tid];
    const float4* ag4 = (const float4*)agg;
#pragma unroll
    for (int i = 0; i < 2; ++i) {
        int idx = tid + i * 256;
        int m = idx >> 4, kq = idx & 15;
        int nn = n0 + m;
        float4 v = make_float4(0.f, 0.f, 0.f, 0.f);
        if (nn < N_NODES) v = ag4[nn * 16 + kq];
        *(float4*)&as[m * 68 + kq * 4] = v;
    }
    __syncthreads();
    int j0 = (tid & 31) * 4;
    int m0 = (tid >> 5) * 4;
    float acc[4][4] = {};
#pragma unroll 8
    for (int k = 0; k < 64; ++k) {
        float4 w = *(const float4*)&w1s[k * 128 + j0];
        float a0 = as[(m0 + 0) * 68 + k];
        float a1 = as[(m0 + 1) * 68 + k];
        float a2 = as[(m0 + 2) * 68 + k];
        float a3 = as[(m0 + 3) * 68 + k];
        acc[0][0] = fmaf(a0, w.x, acc[0][0]); acc[0][1] = fmaf(a0, w.y, acc[0][1]);
        acc[0][2] = fmaf(a0, w.z, acc[0][2]); acc[0][3] = fmaf(a0, w.w, acc[0][3]);
        acc[1][0] = fmaf(a1, w.x, acc[1][0]); acc[1][1] = fmaf(a1, w.y, acc[1][1]);
        acc[1][2] = fmaf(a1, w.z, acc[1][2]); acc[1][3] = fmaf(a1, w.w, acc[1][3]);
        acc[2][0] = fmaf(a2, w.x, acc[2][0]); acc[2][1] = fmaf(a2, w.y, acc[2][1]);
        acc[2][2] = fmaf(a2, w.z, acc[2][2]); acc[2][3] = fmaf(a2, w.w, acc[2][3]);
        acc[3][0] = fmaf(a3, w.x, acc[3][0]); acc[3][1] = fmaf(a3, w.y, acc[3][1]);
        acc[3][2] = fmaf(a3, w.z, acc[3][2]); acc[3][3] = fmaf(a3, w.w, acc[3][3]);
    }
#pragma unroll
    for (int a = 0; a < 4; ++a) {
        int nn = n0 + m0 + a;
        if (nn < N_NODES) {
            float4 o;
            o.x = fmaxf(acc[a][0] + b1s[j0 + 0], 0.f);
            o.y = fmaxf(acc[a][1] + b1s[j0 + 1], 0.f);
            o.z = fmaxf(acc[a][2] + b1s[j0 + 2], 0.f);
            o.w = fmaxf(acc[a][3] + b1s[j0 + 3], 0.f);
            *(float4*)&hidden[nn * HID + j0] = o;
        }
    }
}

// h2 = hidden @ W2 + b2, PLUS fused BN-stats reduction (removes k_stats pass)
__global__ __launch_bounds__(256) void k_mlp2(const float* __restrict__ hidden,
                                              float* __restrict__ h2,
                                              const float* __restrict__ W2l,
                                              const float* __restrict__ b2l,
                                              float* __restrict__ stats) {
    __shared__ float w2s[128 * 64];
    __shared__ float hs[64 * 132];
    __shared__ float b2s[64];
    int tid = threadIdx.x;
    int n0 = blockIdx.x * 64;
    const float4* wg = (const float4*)W2l;
    float4* wsh = (float4*)w2s;
#pragma unroll
    for (int i = 0; i < 8; ++i) wsh[tid + i * 256] = wg[tid + i * 256];
    if (tid < 64) b2s[tid] = b2l[tid];
    const float4* hg4 = (const float4*)hidden;
#pragma unroll
    for (int i = 0; i < 8; ++i) {
        int idx = tid + i * 256;
        int m = idx >> 5, kq = idx & 31;
        int nn = n0 + m;
        float4 v = make_float4(0.f, 0.f, 0.f, 0.f);
        if (nn < N_NODES) v = hg4[nn * 32 + kq];
        *(float4*)&hs[m * 132 + kq * 4] = v;
    }
    __syncthreads();
    int f0 = (tid & 15) * 4;
    int m0 = (tid >> 4) * 4;
    float acc[4][4] = {};
#pragma unroll 8
    for (int k = 0; k < 128; ++k) {
        float4 w = *(const float4*)&w2s[k * 64 + f0];
        float a0 = hs[(m0 + 0) * 132 + k];
        float a1 = hs[(m0 + 1) * 132 + k];
        float a2 = hs[(m0 + 2) * 132 + k];
        float a3 = hs[(m0 + 3) * 132 + k];
        acc[0][0] = fmaf(a0, w.x, acc[0][0]); acc[0][1] = fmaf(a0, w.y, acc[0][1]);
        acc[0][2] = fmaf(a0, w.z, acc[0][2]); acc[0][3] = fmaf(a0, w.w, acc[0][3]);
        acc[1][0] = fmaf(a1, w.x, acc[1][0]); acc[1][1] = fmaf(a1, w.y, acc[1][1]);
        acc[1][2] = fmaf(a1, w.z, acc[1][2]); acc[1][3] = fmaf(a1, w.w, acc[1][3]);
        acc[2][0] = fmaf(a2, w.x, acc[2][0]); acc[2][1] = fmaf(a2, w.y, acc[2][1]);
        acc[2][2] = fmaf(a2, w.z, acc[2][2]); acc[2][3] = fmaf(a2, w.w, acc[2][3]);
        acc[3][0] = fmaf(a3, w.x, acc[3][0]); acc[3][1] = fmaf(a3, w.y, acc[3][1]);
        acc[3][2] = fmaf(a3, w.z, acc[3][2]); acc[3][3] = fmaf(a3, w.w, acc[3][3]);
    }
    float sf[4] = {0.f, 0.f, 0.f, 0.f}, qf[4] = {0.f, 0.f, 0.f, 0.f};
#pragma unroll
    for (int a = 0; a < 4; ++a) {
        int nn = n0 + m0 + a;
        if (nn < N_NODES) {
            float v0 = acc[a][0] + b2s[f0 + 0];
            float v1 = acc[a][1] + b2s[f0 + 1];
            float v2 = acc[a][2] + b2s[f0 + 2];
            float v3 = acc[a][3] + b2s[f0 + 3];
            *(float4*)&h2[nn * EMB + f0] = make_float4(v0, v1, v2, v3);
            sf[0] += v0; sf[1] += v1; sf[2] += v2; sf[3] += v3;
            qf[0] = fmaf(v0, v0, qf[0]); qf[1] = fmaf(v1, v1, qf[1]);
            qf[2] = fmaf(v2, v2, qf[2]); qf[3] = fmaf(v3, v3, qf[3]);
        }
    }
    // block-level stats reduction, reusing hs LDS (done with it)
    __syncthreads();
    float* red = hs;  // [0..1023]=sum[mg][f], [1024..2047]=sq[mg][f]
    int mg = tid >> 4;
#pragma unroll
    for (int j = 0; j < 4; ++j) {
        red[mg * 64 + f0 + j] = sf[j];
        red[1024 + mg * 64 + f0 + j] = qf[j];
    }
    __syncthreads();
    if (tid < 64) {
        float s = 0.f, q = 0.f;
#pragma unroll
        for (int m = 0; m < 16; ++m) {
            s += red[m * 64 + tid];
            q += red[1024 + m * 64 + tid];
        }
        atomAddF(&stats[tid], s);
        atomAddF(&stats[64 + tid], q);
    }
}

// BN apply (+ ELU except last layer)
__global__ void k_bn(const float* __restrict__ h2, float* __restrict__ h,
                     const float* __restrict__ stats, const float* __restrict__ gam,
                     const float* __restrict__ bet, int apply_elu) {
    int gid = blockIdx.x * 256 + threadIdx.x;
    if (gid >= N_NODES * EMB) return;
    int f = gid & 63;
    const float invN = 1.f / (float)N_NODES;
    float mean = stats[f] * invN;
    float var = stats[64 + f] * invN - mean * mean;
    float inv = rsqrtf(var + BN_EPS);
    float v = (h2[gid] - mean) * inv * gam[f] + bet[f];
    if (apply_elu) v = v > 0.f ? v : expm1f(v);
    h[gid] = v;
}

__global__ void k_out(const float* __restrict__ h, const int* __restrict__ last,
                      float* __restrict__ out) {
    int gid = blockIdx.x * 256 + threadIdx.x;
    if (gid >= NGRAPH * EMB) return;
    int b = gid >> 6, f = gid & 63;
    out[gid] = h[last[b] * EMB + f];
}

extern "C" void kernel_launch(void* const* d_in, const int* in_sizes, int n_in,
                              void* d_out, int out_size, void* d_ws, size_t ws_size,
                              hipStream_t stream) {
    const float* x   = (const float*)d_in[0];
    const float* ea  = (const float*)d_in[1];
    const int*   eidx= (const int*)d_in[2];
    const int*   last= (const int*)d_in[3];
    const float* xW  = (const float*)d_in[4];
    const float* xb  = (const float*)d_in[5];
    const float* eW  = (const float*)d_in[6];
    const float* eb  = (const float*)d_in[7];
    const float* W1  = (const float*)d_in[8];
    const float* b1  = (const float*)d_in[9];
    const float* W2  = (const float*)d_in[10];
    const float* b2  = (const float*)d_in[11];
    const float* gam = (const float*)d_in[12];
    const float* bet = (const float*)d_in[13];
    float* out = (float*)d_out;

    const int* srcI = eidx;
    const int* dstI = eidx + N_EDGES;

    float* h      = (float*)d_ws;              // N*64
    float* agg    = h + N_NODES * EMB;         // N*64 (reused as h2)
    float* hidden = agg + N_NODES * EMB;       // N*128
    float* aggE   = hidden + N_NODES * HID;    // N*5
    float* stats  = aggE + N_NODES * EFD;      // L*128
    int* deg      = (int*)(stats + NLAYER * 2 * EMB);  // N
    int* rowstart = deg + N_NODES;             // N+1
    int* cursor   = rowstart + N_NODES + 1;    // N
    int* csr      = cursor + N_NODES;          // E
    int* bsum     = csr + N_EDGES;             // NB_SCAN
    int* boff     = bsum + NB_SCAN;            // NB_SCAN
    int* csrE     = (int*)hidden;              // E (alias, pre-layer-loop only)

    hipMemsetAsync(deg, 0, N_NODES * sizeof(int), stream);
    hipMemsetAsync(stats, 0, NLAYER * 2 * EMB * sizeof(float), stream);

    k_input<<<(N_NODES * EMB + 255) / 256, 256, 0, stream>>>(x, xW, xb, h);
    k_hist<<<(N_EDGES + 255) / 256, 256, 0, stream>>>(dstI, deg);
    k_scanA<<<NB_SCAN, 256, 0, stream>>>(deg, bsum);
    k_scanB<<<1, 256, 0, stream>>>(bsum, boff);
    k_scanC<<<NB_SCAN, 256, 0, stream>>>(deg, boff, rowstart, cursor);
    k_fill<<<(N_EDGES + 255) / 256, 256, 0, stream>>>(srcI, dstI, cursor, csr, csrE);
    k_aggE<<<(N_NODES * 64 + 255) / 256, 256, 0, stream>>>(rowstart, csrE, ea, aggE);

    for (int l = 0; l < NLAYER; ++l) {
        k_agg<<<(N_NODES * 64 + 255) / 256, 256, 0, stream>>>(
            h, agg, rowstart, csr, aggE, eW + l * EFD * EMB, eb + l * EMB);
        k_mlp1<<<(N_NODES + 31) / 32, 256, 0, stream>>>(agg, hidden, W1 + l * EMB * HID,
                                                        b1 + l * HID);
        k_mlp2<<<(N_NODES + 63) / 64, 256, 0, stream>>>(hidden, agg, W2 + l * HID * EMB,
                                                        b2 + l * EMB, stats + l * 2 * EMB);
        k_bn<<<(N_NODES * EMB + 255) / 256, 256, 0, stream>>>(
            agg, h, stats + l * 2 * EMB, gam + l * EMB, bet + l * EMB,
            (l < NLAYER - 1) ? 1 : 0);
    }
    k_out<<<(NGRAPH * EMB + 255) / 256, 256, 0, stream>>>(h, last, out);
}